// Round 1
// baseline (132.987 us; speedup 1.0000x reference)
//
#include <hip/hip_runtime.h>

typedef __bf16 bf16;
typedef __bf16 bf16x8 __attribute__((ext_vector_type(8)));
typedef __bf16 bf16x4 __attribute__((ext_vector_type(4)));
typedef float f32x4 __attribute__((ext_vector_type(4)));

#define MFMA16(a, b, c) __builtin_amdgcn_mfma_f32_16x16x32_bf16((a), (b), (c), 0, 0, 0)

__device__ __forceinline__ void gload_lds16(const void* g, void* l) {
  __builtin_amdgcn_global_load_lds(
      (const __attribute__((address_space(1))) void*)g,
      (__attribute__((address_space(3))) void*)l, 16, 0, 0);
}

// ---------------- f32 -> bf16 convert (vectorized) ----------------
__global__ __launch_bounds__(256) void cvt_f32_bf16(const float* __restrict__ s,
                                                    bf16* __restrict__ d, int n) {
  int i = (blockIdx.x * 256 + threadIdx.x) * 4;
  const int stride = gridDim.x * 256 * 4;
  for (; i < n; i += stride) {
    f32x4 v = *(const f32x4*)(s + i);
    bf16x4 o;
    o[0] = (bf16)v[0]; o[1] = (bf16)v[1]; o[2] = (bf16)v[2]; o[3] = (bf16)v[3];
    *(bf16x4*)(d + i) = o;
  }
}

// ---------------- Gaussian mask table: g[idx] = exp(-(idx-511)^2/(delta^2+EPS)) / sqrt(F) ----------------
__global__ void gtab_k(const float* __restrict__ delta, float* __restrict__ g) {
  int i = blockIdx.x * 256 + threadIdx.x;
  if (i >= 1535) return;
  float dl = delta[0];
  float inv = 1.0f / (dl * dl + 1e-8f);
  float diff = (float)(i - 511);
  g[i] = expf(-diff * diff * inv) * 0.04419417382415922f;  // 1/sqrt(512)
}

// ---------------- cache -> bf16 K rows [0,512) and V^T cols [0,512) ----------------
__global__ __launch_bounds__(256) void cache_prep(const float* __restrict__ ck,
                                                  const float* __restrict__ cv,
                                                  bf16* __restrict__ kk,
                                                  bf16* __restrict__ vt) {
  const int hb = blockIdx.y;
  const int st = blockIdx.x;  // 0..7, each covers 64 s
  const int tid = threadIdx.x;
  __shared__ bf16 tl[64][65];
  const int s0 = st * 64;
#pragma unroll
  for (int it = 0; it < 16; ++it) {
    int idx = it * 256 + tid;
    int sl = idx >> 6, dd = idx & 63;
    float kval = ck[((size_t)hb * 1024 + 512 + s0 + sl) * 64 + dd];
    kk[((size_t)hb * 1024 + s0 + sl) * 64 + dd] = (bf16)kval;
    float vval = cv[((size_t)hb * 1024 + 512 + s0 + sl) * 64 + dd];
    tl[sl][dd] = (bf16)vval;
  }
  __syncthreads();
#pragma unroll
  for (int it = 0; it < 16; ++it) {
    int idx = it * 256 + tid;
    int dl = idx >> 6, sl = idx & 63;
    vt[((size_t)hb * 64 + dl) * 1024 + s0 + sl] = tl[sl][dl];
  }
}

// ---------------- GEMM: C = A(Mx512) @ B(Nx512)^T + bias, 128x128 tile, m97-style ----------------
// MODE 0: -> qh[(h*8+b)][t][d] bf16      MODE 1: -> kk[(h*8+b)][512+t][d] bf16
// MODE 2: -> vT[(h*8+b)][d][512+t] bf16  MODE 3: -> out fp32 [m][n]
template <int MODE>
__global__ __launch_bounds__(256) void gemm_bt(const bf16* __restrict__ A,
                                               const bf16* __restrict__ Bm,
                                               const float* __restrict__ bias,
                                               void* __restrict__ out) {
  constexpr int K = 512;
  __shared__ bf16 As[128 * 32];
  __shared__ bf16 Bs[128 * 32];
  const int tid = threadIdx.x;
  const int lane = tid & 63;
  const int wave = tid >> 6;
  const int wr = wave >> 1, wc = wave & 1;
  const int l15 = lane & 15, lg = lane >> 4;
  const int mbase = blockIdx.x * 128;
  const int nbase = blockIdx.y * 128;
  f32x4 acc[4][4] = {};

  for (int k0 = 0; k0 < K; k0 += 32) {
    __syncthreads();
#pragma unroll
    for (int it = 0; it < 2; ++it) {
      int o = (it * 256 + tid) * 16;  // byte offset in 8KB tile
      int row = o >> 6;
      int cb = o & 63;
      gload_lds16((const char*)(A + (size_t)(mbase + row) * K + k0) + cb, (char*)As + o);
      gload_lds16((const char*)(Bm + (size_t)(nbase + row) * K + k0) + cb, (char*)Bs + o);
    }
    __syncthreads();
    bf16x8 af[4], bfr[4];
#pragma unroll
    for (int i = 0; i < 4; ++i)
      af[i] = *(const bf16x8*)(As + (wr * 64 + i * 16 + l15) * 32 + lg * 8);
#pragma unroll
    for (int j = 0; j < 4; ++j)
      bfr[j] = *(const bf16x8*)(Bs + (wc * 64 + j * 16 + l15) * 32 + lg * 8);
#pragma unroll
    for (int i = 0; i < 4; ++i)
#pragma unroll
      for (int j = 0; j < 4; ++j)
        acc[i][j] = MFMA16(af[i], bfr[j], acc[i][j]);
  }

#pragma unroll
  for (int j = 0; j < 4; ++j) {
    const int nc = nbase + wc * 64 + j * 16 + l15;
    const float bv = bias[nc];
    const int h = nc >> 6, dd = nc & 63;
#pragma unroll
    for (int i = 0; i < 4; ++i) {
#pragma unroll
      for (int r = 0; r < 4; ++r) {
        const int mr = mbase + wr * 64 + i * 16 + lg * 4 + r;
        const float v = acc[i][j][r] + bv;
        const int bb = mr >> 9, t = mr & 511;
        if constexpr (MODE == 0) {
          ((bf16*)out)[(((size_t)(h * 8 + bb) * 512 + t) << 6) + dd] = (bf16)v;
        } else if constexpr (MODE == 1) {
          ((bf16*)out)[(((size_t)(h * 8 + bb) * 1024 + 512 + t) << 6) + dd] = (bf16)v;
        } else if constexpr (MODE == 2) {
          ((bf16*)out)[(((size_t)(h * 8 + bb) * 64 + dd) << 10) + 512 + t] = (bf16)v;
        } else {
          ((float*)out)[(size_t)mr * 512 + nc] = v;
        }
      }
    }
  }
}

// ---------------- Flash attention: per (hb, 64-q-tile), 4 waves x 16 q rows ----------------
__global__ __launch_bounds__(256) void attn_k(const bf16* __restrict__ qh,
                                              const bf16* __restrict__ kk,
                                              const bf16* __restrict__ vt,
                                              const float* __restrict__ gtab,
                                              bf16* __restrict__ ao) {
  const int hb = blockIdx.y;
  const int qt = blockIdx.x;
  const int tid = threadIdx.x;
  const int lane = tid & 63;
  const int wave = tid >> 6;
  const int l15 = lane & 15;
  const int lg = lane >> 4;

  __shared__ float gl[1536];
  __shared__ bf16 pl[4][16][40];  // P scratch per wave, padded pitch for bank spread

  for (int i = tid; i < 1535; i += 256) gl[i] = gtab[i];

  const int qbase = qt * 64 + wave * 16;
  const bf16* qrow = qh + ((size_t)hb * 512 + qbase + l15) * 64;
  bf16x8 aq0 = *(const bf16x8*)(qrow + lg * 8);
  bf16x8 aq1 = *(const bf16x8*)(qrow + 32 + lg * 8);
  __syncthreads();

  float m_r[4], l_r[4];
  f32x4 acco[4] = {};
#pragma unroll
  for (int r = 0; r < 4; ++r) { m_r[r] = -1.0e30f; l_r[r] = 0.f; }
  const int tb = qbase + lg * 4;  // C-layout row r -> query t = tb + r

  for (int sb = 0; sb < 1024; sb += 32) {
    const bf16* kr = kk + ((size_t)hb * 1024 + sb) * 64;
    bf16x8 b00 = *(const bf16x8*)(kr + l15 * 64 + lg * 8);
    bf16x8 b01 = *(const bf16x8*)(kr + l15 * 64 + 32 + lg * 8);
    bf16x8 b10 = *(const bf16x8*)(kr + (16 + l15) * 64 + lg * 8);
    bf16x8 b11 = *(const bf16x8*)(kr + (16 + l15) * 64 + 32 + lg * 8);
    f32x4 s0 = {0.f, 0.f, 0.f, 0.f};
    f32x4 s1 = {0.f, 0.f, 0.f, 0.f};
    s0 = MFMA16(aq0, b00, s0);
    s0 = MFMA16(aq1, b01, s0);
    s1 = MFMA16(aq0, b10, s1);
    s1 = MFMA16(aq1, b11, s1);

    float x0[4], x1[4], cm[4];
#pragma unroll
    for (int r = 0; r < 4; ++r) {
      int t = tb + r;
      x0[r] = s0[r] * gl[1023 + t - (sb + l15)];
      x1[r] = s1[r] * gl[1023 + t - (sb + 16 + l15)];
      cm[r] = fmaxf(x0[r], x1[r]);
    }
#pragma unroll
    for (int mk = 1; mk < 16; mk <<= 1)
#pragma unroll
      for (int r = 0; r < 4; ++r)
        cm[r] = fmaxf(cm[r], __shfl_xor(cm[r], mk, 64));

    float fac[4], ps[4];
#pragma unroll
    for (int r = 0; r < 4; ++r) {
      float mn = fmaxf(m_r[r], cm[r]);
      fac[r] = __expf(m_r[r] - mn);
      m_r[r] = mn;
      x0[r] = __expf(x0[r] - mn);
      x1[r] = __expf(x1[r] - mn);
      ps[r] = x0[r] + x1[r];
    }
#pragma unroll
    for (int mk = 1; mk < 16; mk <<= 1)
#pragma unroll
      for (int r = 0; r < 4; ++r)
        ps[r] += __shfl_xor(ps[r], mk, 64);
#pragma unroll
    for (int r = 0; r < 4; ++r) l_r[r] = l_r[r] * fac[r] + ps[r];
#pragma unroll
    for (int dg = 0; dg < 4; ++dg)
#pragma unroll
      for (int r = 0; r < 4; ++r) acco[dg][r] *= fac[r];

    // P -> LDS (layout flip to A-fragment order), then PV
#pragma unroll
    for (int r = 0; r < 4; ++r) {
      pl[wave][lg * 4 + r][l15] = (bf16)x0[r];
      pl[wave][lg * 4 + r][16 + l15] = (bf16)x1[r];
    }
    asm volatile("s_waitcnt lgkmcnt(0)" ::: "memory");
    bf16x8 pa = *(const bf16x8*)(&pl[wave][l15][lg * 8]);
    const bf16* vr = vt + (size_t)hb * 64 * 1024 + sb;
#pragma unroll
    for (int dg = 0; dg < 4; ++dg) {
      bf16x8 bv = *(const bf16x8*)(vr + (size_t)(dg * 16 + l15) * 1024 + lg * 8);
      acco[dg] = MFMA16(pa, bv, acco[dg]);
    }
    asm volatile("" ::: "memory");
  }

  const int b = hb & 7;
  const int h = hb >> 3;
#pragma unroll
  for (int r = 0; r < 4; ++r) {
    float inv = 1.0f / l_r[r];
    int t = tb + r;
    bf16* orow = ao + ((size_t)(b * 512 + t) * 512) + h * 64;
#pragma unroll
    for (int dg = 0; dg < 4; ++dg)
      orow[dg * 16 + l15] = (bf16)(acco[dg][r] * inv);
  }
}

extern "C" void kernel_launch(void* const* d_in, const int* in_sizes, int n_in,
                              void* d_out, int out_size, void* d_ws, size_t ws_size,
                              hipStream_t stream) {
  const float* x = (const float*)d_in[0];
  const float* Wq = (const float*)d_in[1];
  const float* bq = (const float*)d_in[2];
  const float* Wk = (const float*)d_in[3];
  const float* bk = (const float*)d_in[4];
  const float* Wv = (const float*)d_in[5];
  const float* bv = (const float*)d_in[6];
  const float* Wo = (const float*)d_in[7];
  const float* bo = (const float*)d_in[8];
  const float* delta = (const float*)d_in[9];
  const float* ck = (const float*)d_in[10];
  const float* cv = (const float*)d_in[11];

  char* w = (char*)d_ws;
  auto carve = [&](size_t bytes) {
    char* p = w;
    w += (bytes + 255) & ~(size_t)255;
    return p;
  };
  bf16* xb = (bf16*)carve((size_t)4096 * 512 * 2);
  bf16* wqb = (bf16*)carve((size_t)512 * 512 * 2);
  bf16* wkb = (bf16*)carve((size_t)512 * 512 * 2);
  bf16* wvb = (bf16*)carve((size_t)512 * 512 * 2);
  bf16* wob = (bf16*)carve((size_t)512 * 512 * 2);
  bf16* qhb = (bf16*)carve((size_t)64 * 512 * 64 * 2);
  bf16* kkb = (bf16*)carve((size_t)64 * 1024 * 64 * 2);
  bf16* vtb = (bf16*)carve((size_t)64 * 64 * 1024 * 2);
  bf16* aob = (bf16*)carve((size_t)4096 * 512 * 2);
  float* gt = (float*)carve(1536 * 4);

  cvt_f32_bf16<<<2048, 256, 0, stream>>>(x, xb, 4096 * 512);
  cvt_f32_bf16<<<256, 256, 0, stream>>>(Wq, wqb, 512 * 512);
  cvt_f32_bf16<<<256, 256, 0, stream>>>(Wk, wkb, 512 * 512);
  cvt_f32_bf16<<<256, 256, 0, stream>>>(Wv, wvb, 512 * 512);
  cvt_f32_bf16<<<256, 256, 0, stream>>>(Wo, wob, 512 * 512);
  gtab_k<<<6, 256, 0, stream>>>(delta, gt);
  cache_prep<<<dim3(8, 64), 256, 0, stream>>>(ck, cv, kkb, vtb);
  gemm_bt<0><<<dim3(32, 4), 256, 0, stream>>>(xb, wqb, bq, qhb);
  gemm_bt<1><<<dim3(32, 4), 256, 0, stream>>>(xb, wkb, bk, kkb);
  gemm_bt<2><<<dim3(32, 4), 256, 0, stream>>>(xb, wvb, bv, vtb);
  attn_k<<<dim3(8, 64), 256, 0, stream>>>(qhb, kkb, vtb, gt, aob);
  gemm_bt<3><<<dim3(32, 4), 256, 0, stream>>>(aob, wob, bo, d_out);
}

// Round 2
// 106.856 us; speedup vs baseline: 1.2445x; 1.2445x over previous
//
#include <hip/hip_runtime.h>

typedef __bf16 bf16;
typedef __bf16 bf16x8 __attribute__((ext_vector_type(8)));
typedef __bf16 bf16x4 __attribute__((ext_vector_type(4)));
typedef float f32x4 __attribute__((ext_vector_type(4)));

#define MFMA16(a, b, c) __builtin_amdgcn_mfma_f32_16x16x32_bf16((a), (b), (c), 0, 0, 0)

__device__ __forceinline__ void gload_lds16(const void* g, void* l) {
  __builtin_amdgcn_global_load_lds(
      (const __attribute__((address_space(1))) void*)g,
      (__attribute__((address_space(3))) void*)l, 16, 0, 0);
}

// ---------------- x: f32 -> bf16 convert (vectorized) ----------------
__global__ __launch_bounds__(256) void cvt_f32_bf16(const float* __restrict__ s,
                                                    bf16* __restrict__ d, int n) {
  int i = (blockIdx.x * 256 + threadIdx.x) * 4;
  const int stride = gridDim.x * 256 * 4;
  for (; i < n; i += stride) {
    f32x4 v = *(const f32x4*)(s + i);
    bf16x4 o;
    o[0] = (bf16)v[0]; o[1] = (bf16)v[1]; o[2] = (bf16)v[2]; o[3] = (bf16)v[3];
    *(bf16x4*)(d + i) = o;
  }
}

// ---------------- 4 weights f32->bf16 + Gaussian table, one launch ----------------
__global__ __launch_bounds__(256) void cvt_w4(const float* __restrict__ w0, const float* __restrict__ w1,
                                              const float* __restrict__ w2, const float* __restrict__ w3,
                                              bf16* __restrict__ o0, bf16* __restrict__ o1,
                                              bf16* __restrict__ o2, bf16* __restrict__ o3,
                                              const float* __restrict__ delta, float* __restrict__ gt) {
  const int y = blockIdx.y;
  if (y == 4) {
    int i = blockIdx.x * 256 + threadIdx.x;
    if (i < 1535) {
      float dl = delta[0];
      float inv = 1.0f / (dl * dl + 1e-8f);
      float diff = (float)(i - 511);
      gt[i] = __expf(-diff * diff * inv) * 0.04419417382415922f;  // includes 1/sqrt(512)
    }
    return;
  }
  const float* s = y == 0 ? w0 : y == 1 ? w1 : y == 2 ? w2 : w3;
  bf16* d = y == 0 ? o0 : y == 1 ? o1 : y == 2 ? o2 : o3;
  int i = (blockIdx.x * 256 + threadIdx.x) * 4;  // grid.x=256 covers 512*512
  f32x4 v = *(const f32x4*)(s + i);
  bf16x4 o;
  o[0] = (bf16)v[0]; o[1] = (bf16)v[1]; o[2] = (bf16)v[2]; o[3] = (bf16)v[3];
  *(bf16x4*)(d + i) = o;
}

// ---------------- cache -> bf16 K rows [0,512) and V^T cols [0,512) ----------------
__global__ __launch_bounds__(256) void cache_prep(const float* __restrict__ ck,
                                                  const float* __restrict__ cv,
                                                  bf16* __restrict__ kk,
                                                  bf16* __restrict__ vt) {
  const int hb = blockIdx.y;
  const int st = blockIdx.x;  // 0..7, each covers 64 s
  const int tid = threadIdx.x;
  __shared__ bf16 tl[64][65];
  const int s0 = st * 64;
#pragma unroll
  for (int it = 0; it < 16; ++it) {
    int idx = it * 256 + tid;
    int sl = idx >> 6, dd = idx & 63;
    float kval = ck[((size_t)hb * 1024 + 512 + s0 + sl) * 64 + dd];
    kk[((size_t)hb * 1024 + s0 + sl) * 64 + dd] = (bf16)kval;
    float vval = cv[((size_t)hb * 1024 + 512 + s0 + sl) * 64 + dd];
    tl[sl][dd] = (bf16)vval;
  }
  __syncthreads();
#pragma unroll
  for (int it = 0; it < 16; ++it) {
    int idx = it * 256 + tid;
    int dl = idx >> 6, sl = idx & 63;
    vt[((size_t)hb * 64 + dl) * 1024 + s0 + sl] = tl[sl][dl];
  }
}

// ---------------- fused QKV projection GEMM: 64x64 tiles, grid (64, 24) ----------------
// n-tile y: matrix id = (y*64)>>9 (0=Q,1=K,2=V); routes epilogue per matrix.
__global__ __launch_bounds__(256) void qkv_gemm(const bf16* __restrict__ xb,
                                                const bf16* __restrict__ wq, const bf16* __restrict__ wk,
                                                const bf16* __restrict__ wv,
                                                const float* __restrict__ bq, const float* __restrict__ bk,
                                                const float* __restrict__ bv,
                                                bf16* __restrict__ qh, bf16* __restrict__ kk,
                                                bf16* __restrict__ vt) {
  __shared__ bf16 As[64 * 32];
  __shared__ bf16 Bs[64 * 32];
  const int tid = threadIdx.x;
  const int lane = tid & 63;
  const int wave = tid >> 6;
  const int wr = wave >> 1, wc = wave & 1;
  const int l15 = lane & 15, lg = lane >> 4;
  const int mbase = blockIdx.x * 64;
  const int nfull = blockIdx.y * 64;
  const int mid = nfull >> 9;
  const int nbase = nfull & 511;
  const bf16* W = mid == 0 ? wq : (mid == 1 ? wk : wv);
  const float* bias = mid == 0 ? bq : (mid == 1 ? bk : bv);
  f32x4 acc[2][2] = {};

  const int o = tid * 16;        // byte offset in 4KB tile
  const int row = o >> 6;        // 64B per row (32 k * 2B)
  const int cb = o & 63;
  for (int k0 = 0; k0 < 512; k0 += 32) {
    __syncthreads();
    gload_lds16((const char*)(xb + (size_t)(mbase + row) * 512 + k0) + cb, (char*)As + o);
    gload_lds16((const char*)(W + (size_t)(nbase + row) * 512 + k0) + cb, (char*)Bs + o);
    __syncthreads();
    bf16x8 af[2], bfr[2];
#pragma unroll
    for (int i = 0; i < 2; ++i)
      af[i] = *(const bf16x8*)(As + (wr * 32 + i * 16 + l15) * 32 + lg * 8);
#pragma unroll
    for (int j = 0; j < 2; ++j)
      bfr[j] = *(const bf16x8*)(Bs + (wc * 32 + j * 16 + l15) * 32 + lg * 8);
#pragma unroll
    for (int i = 0; i < 2; ++i)
#pragma unroll
      for (int j = 0; j < 2; ++j)
        acc[i][j] = MFMA16(af[i], bfr[j], acc[i][j]);
  }

#pragma unroll
  for (int j = 0; j < 2; ++j) {
    const int nn = nbase + wc * 32 + j * 16 + l15;
    const float bvv = bias[nn];
    const int h = nn >> 6, dd = nn & 63;
#pragma unroll
    for (int i = 0; i < 2; ++i) {
#pragma unroll
      for (int r = 0; r < 4; ++r) {
        const int mr = mbase + wr * 32 + i * 16 + lg * 4 + r;
        const float v = acc[i][j][r] + bvv;
        const int bb = mr >> 9, t = mr & 511;
        if (mid == 0) {
          qh[(((size_t)(h * 8 + bb) * 512 + t) << 6) + dd] = (bf16)v;
        } else if (mid == 1) {
          kk[(((size_t)(h * 8 + bb) * 1024 + 512 + t) << 6) + dd] = (bf16)v;
        } else {
          vt[(((size_t)(h * 8 + bb) * 64 + dd) << 10) + 512 + t] = (bf16)v;
        }
      }
    }
  }
}

// ---------------- output projection GEMM: 64x64 tiles, fp32 out, grid (64, 8) ----------------
__global__ __launch_bounds__(256) void out_gemm(const bf16* __restrict__ A,
                                                const bf16* __restrict__ W,
                                                const float* __restrict__ bias,
                                                float* __restrict__ out) {
  __shared__ bf16 As[64 * 32];
  __shared__ bf16 Bs[64 * 32];
  const int tid = threadIdx.x;
  const int lane = tid & 63;
  const int wave = tid >> 6;
  const int wr = wave >> 1, wc = wave & 1;
  const int l15 = lane & 15, lg = lane >> 4;
  const int mbase = blockIdx.x * 64;
  const int nbase = blockIdx.y * 64;
  f32x4 acc[2][2] = {};

  const int o = tid * 16;
  const int row = o >> 6;
  const int cb = o & 63;
  for (int k0 = 0; k0 < 512; k0 += 32) {
    __syncthreads();
    gload_lds16((const char*)(A + (size_t)(mbase + row) * 512 + k0) + cb, (char*)As + o);
    gload_lds16((const char*)(W + (size_t)(nbase + row) * 512 + k0) + cb, (char*)Bs + o);
    __syncthreads();
    bf16x8 af[2], bfr[2];
#pragma unroll
    for (int i = 0; i < 2; ++i)
      af[i] = *(const bf16x8*)(As + (wr * 32 + i * 16 + l15) * 32 + lg * 8);
#pragma unroll
    for (int j = 0; j < 2; ++j)
      bfr[j] = *(const bf16x8*)(Bs + (wc * 32 + j * 16 + l15) * 32 + lg * 8);
#pragma unroll
    for (int i = 0; i < 2; ++i)
#pragma unroll
      for (int j = 0; j < 2; ++j)
        acc[i][j] = MFMA16(af[i], bfr[j], acc[i][j]);
  }

#pragma unroll
  for (int j = 0; j < 2; ++j) {
    const int nn = nbase + wc * 32 + j * 16 + l15;
    const float bvv = bias[nn];
#pragma unroll
    for (int i = 0; i < 2; ++i) {
#pragma unroll
      for (int r = 0; r < 4; ++r) {
        const int mr = mbase + wr * 32 + i * 16 + lg * 4 + r;
        out[(size_t)mr * 512 + nn] = acc[i][j][r] + bvv;
      }
    }
  }
}

// ---------------- Flash attention: 512 threads = 2 q-subtiles x 4 KV-quarters ----------------
// grid (16, 64): 32 q per block. Each wave: 16 q x 256 kv, KVBLK=64, flash accumulation.
// In-block LDS merge of the 4 KV-quarter partials.
__global__ __launch_bounds__(512, 4) void attn_k(const bf16* __restrict__ qh,
                                                 const bf16* __restrict__ kk,
                                                 const bf16* __restrict__ vt,
                                                 const float* __restrict__ gtab,
                                                 bf16* __restrict__ ao) {
  const int hb = blockIdx.y;
  const int qt = blockIdx.x;
  const int tid = threadIdx.x;
  const int lane = tid & 63;
  const int wave = tid >> 6;
  const int qs = wave & 1;   // q subtile (16 rows)
  const int kq = wave >> 1;  // kv quarter (256 cols)
  const int l15 = lane & 15;
  const int lg = lane >> 4;

  __shared__ float gl[1536];
  // union: P-scratch (main loop) / combine buffers (epilogue)
  __shared__ __align__(16) char un[8 * 16 * 72 * 2];  // 36864 B
  bf16 (*pl)[16][72] = (bf16(*)[16][72])un;
  float (*cacc)[16][64] = (float(*)[16][64])un;                 // 6 slots = 24576 B
  float (*cml)[16][2] = (float(*)[16][2])(un + 6 * 16 * 64 * 4);  // +768 B

  for (int i = tid; i < 1535; i += 512) gl[i] = gtab[i];

  const int qbase = qt * 32 + qs * 16;
  const bf16* qrow = qh + ((size_t)hb * 512 + qbase + l15) * 64;
  bf16x8 aq0 = *(const bf16x8*)(qrow + lg * 8);
  bf16x8 aq1 = *(const bf16x8*)(qrow + 32 + lg * 8);
  __syncthreads();

  float m_r[4], l_r[4];
  f32x4 acco[4] = {};
#pragma unroll
  for (int r = 0; r < 4; ++r) { m_r[r] = -1.0e30f; l_r[r] = 0.f; }
  const int tb = qbase + lg * 4;  // C-layout: row r -> query tb + r

  const bf16* vbase = vt + (size_t)hb * 64 * 1024;
  for (int sb = kq * 256; sb < kq * 256 + 256; sb += 64) {
    const bf16* kr = kk + ((size_t)hb * 1024 + sb) * 64;
    f32x4 sc[4] = {};
#pragma unroll
    for (int sq = 0; sq < 4; ++sq) {
      bf16x8 b0 = *(const bf16x8*)(kr + (sq * 16 + l15) * 64 + lg * 8);
      bf16x8 b1 = *(const bf16x8*)(kr + (sq * 16 + l15) * 64 + 32 + lg * 8);
      sc[sq] = MFMA16(aq0, b0, sc[sq]);
      sc[sq] = MFMA16(aq1, b1, sc[sq]);
    }

    float x[4][4], cm[4];
#pragma unroll
    for (int r = 0; r < 4; ++r) {
      int t1023 = 1023 + tb + r - sb;
#pragma unroll
      for (int sq = 0; sq < 4; ++sq)
        x[sq][r] = sc[sq][r] * gl[t1023 - sq * 16 - l15];
      cm[r] = fmaxf(fmaxf(x[0][r], x[1][r]), fmaxf(x[2][r], x[3][r]));
    }
#pragma unroll
    for (int mk = 1; mk < 16; mk <<= 1)
#pragma unroll
      for (int r = 0; r < 4; ++r)
        cm[r] = fmaxf(cm[r], __shfl_xor(cm[r], mk, 64));

    float fac[4], ps[4];
#pragma unroll
    for (int r = 0; r < 4; ++r) {
      float mn = fmaxf(m_r[r], cm[r]);
      fac[r] = __expf(m_r[r] - mn);
      m_r[r] = mn;
#pragma unroll
      for (int sq = 0; sq < 4; ++sq)
        x[sq][r] = __expf(x[sq][r] - mn);
      ps[r] = (x[0][r] + x[1][r]) + (x[2][r] + x[3][r]);
    }
#pragma unroll
    for (int mk = 1; mk < 16; mk <<= 1)
#pragma unroll
      for (int r = 0; r < 4; ++r)
        ps[r] += __shfl_xor(ps[r], mk, 64);
#pragma unroll
    for (int r = 0; r < 4; ++r) l_r[r] = l_r[r] * fac[r] + ps[r];
#pragma unroll
    for (int dg = 0; dg < 4; ++dg)
#pragma unroll
      for (int r = 0; r < 4; ++r) acco[dg][r] *= fac[r];

    // P -> LDS (flip to A-fragment order)
#pragma unroll
    for (int sq = 0; sq < 4; ++sq)
#pragma unroll
      for (int r = 0; r < 4; ++r)
        pl[wave][lg * 4 + r][sq * 16 + l15] = (bf16)x[sq][r];
    asm volatile("s_waitcnt lgkmcnt(0)" ::: "memory");
    __builtin_amdgcn_sched_barrier(0);
    bf16x8 pa0 = *(const bf16x8*)(&pl[wave][l15][lg * 8]);
    bf16x8 pa1 = *(const bf16x8*)(&pl[wave][l15][32 + lg * 8]);
#pragma unroll
    for (int dg = 0; dg < 4; ++dg) {
      const bf16* vr = vbase + (size_t)(dg * 16 + l15) * 1024 + sb;
      bf16x8 bv0 = *(const bf16x8*)(vr + lg * 8);
      bf16x8 bv1 = *(const bf16x8*)(vr + 32 + lg * 8);
      acco[dg] = MFMA16(pa0, bv0, acco[dg]);
      acco[dg] = MFMA16(pa1, bv1, acco[dg]);
    }
    asm volatile("" ::: "memory");
  }

  // merge the 4 KV-quarter partials per q-subtile via LDS
  __syncthreads();  // all P-scratch reads done; reuse as combine buffers
  if (kq > 0) {
    const int slot = (kq - 1) * 2 + qs;
#pragma unroll
    for (int dg = 0; dg < 4; ++dg)
#pragma unroll
      for (int r = 0; r < 4; ++r)
        cacc[slot][lg * 4 + r][dg * 16 + l15] = acco[dg][r];
    if (l15 == 0) {
#pragma unroll
      for (int r = 0; r < 4; ++r) {
        cml[slot][lg * 4 + r][0] = m_r[r];
        cml[slot][lg * 4 + r][1] = l_r[r];
      }
    }
  }
  __syncthreads();
  if (kq == 0) {
#pragma unroll
    for (int p = 0; p < 3; ++p) {
      const int slot = p * 2 + qs;
#pragma unroll
      for (int r = 0; r < 4; ++r) {
        const float mp = cml[slot][lg * 4 + r][0];
        const float lp = cml[slot][lg * 4 + r][1];
        const float M = fmaxf(m_r[r], mp);
        const float f0 = __expf(m_r[r] - M);
        const float fp = __expf(mp - M);
        l_r[r] = l_r[r] * f0 + lp * fp;
        m_r[r] = M;
#pragma unroll
        for (int dg = 0; dg < 4; ++dg)
          acco[dg][r] = acco[dg][r] * f0 + cacc[slot][lg * 4 + r][dg * 16 + l15] * fp;
      }
    }
    const int b = hb & 7;
    const int h = hb >> 3;
#pragma unroll
    for (int r = 0; r < 4; ++r) {
      const float inv = 1.0f / l_r[r];
      const int t = tb + r;
      bf16* orow = ao + ((size_t)(b * 512 + t) * 512) + h * 64;
#pragma unroll
      for (int dg = 0; dg < 4; ++dg)
        orow[dg * 16 + l15] = (bf16)(acco[dg][r] * inv);
    }
  }
}

extern "C" void kernel_launch(void* const* d_in, const int* in_sizes, int n_in,
                              void* d_out, int out_size, void* d_ws, size_t ws_size,
                              hipStream_t stream) {
  const float* x = (const float*)d_in[0];
  const float* Wq = (const float*)d_in[1];
  const float* bq = (const float*)d_in[2];
  const float* Wk = (const float*)d_in[3];
  const float* bk = (const float*)d_in[4];
  const float* Wv = (const float*)d_in[5];
  const float* bv = (const float*)d_in[6];
  const float* Wo = (const float*)d_in[7];
  const float* bo = (const float*)d_in[8];
  const float* delta = (const float*)d_in[9];
  const float* ck = (const float*)d_in[10];
  const float* cv = (const float*)d_in[11];

  char* w = (char*)d_ws;
  auto carve = [&](size_t bytes) {
    char* p = w;
    w += (bytes + 255) & ~(size_t)255;
    return p;
  };
  bf16* xb = (bf16*)carve((size_t)4096 * 512 * 2);
  bf16* wqb = (bf16*)carve((size_t)512 * 512 * 2);
  bf16* wkb = (bf16*)carve((size_t)512 * 512 * 2);
  bf16* wvb = (bf16*)carve((size_t)512 * 512 * 2);
  bf16* wob = (bf16*)carve((size_t)512 * 512 * 2);
  bf16* qhb = (bf16*)carve((size_t)64 * 512 * 64 * 2);
  bf16* kkb = (bf16*)carve((size_t)64 * 1024 * 64 * 2);
  bf16* vtb = (bf16*)carve((size_t)64 * 64 * 1024 * 2);
  bf16* aob = (bf16*)carve((size_t)4096 * 512 * 2);
  float* gt = (float*)carve(1536 * 4);

  cvt_f32_bf16<<<2048, 256, 0, stream>>>(x, xb, 4096 * 512);
  cvt_w4<<<dim3(256, 5), 256, 0, stream>>>(Wq, Wk, Wv, Wo, wqb, wkb, wvb, wob, delta, gt);
  cache_prep<<<dim3(8, 64), 256, 0, stream>>>(ck, cv, kkb, vtb);
  qkv_gemm<<<dim3(64, 24), 256, 0, stream>>>(xb, wqb, wkb, wvb, bq, bk, bv, qhb, kkb, vtb);
  attn_k<<<dim3(16, 64), 512, 0, stream>>>(qhb, kkb, vtb, gt, aob);
  out_gemm<<<dim3(64, 8), 256, 0, stream>>>(aob, wob, bo, (float*)d_out);
}